// Round 3
// baseline (1394.153 us; speedup 1.0000x reference)
//
#include <hip/hip_runtime.h>

#define WS_ALIGN(x) (((x) + 255) & ~(size_t)255)

// ---------------- degree / norm ----------------
__global__ void k_init_deg(int* deg, int N) {
  int i = blockIdx.x * blockDim.x + threadIdx.x;
  if (i < N) deg[i] = 1;  // self-loop
}

__global__ void k_count(const int* __restrict__ dst, int E, int* __restrict__ deg) {
  int e = blockIdx.x * blockDim.x + threadIdx.x;
  if (e < E) atomicAdd(&deg[dst[e]], 1);
}

__global__ void k_dis(const int* __restrict__ deg, float* __restrict__ dis, int N) {
  int i = blockIdx.x * blockDim.x + threadIdx.x;
  if (i < N) dis[i] = rsqrtf((float)deg[i]);
}

__global__ void k_zero(float* __restrict__ p, int n) {
  int i = blockIdx.x * blockDim.x + threadIdx.x;
  if (i < n) p[i] = 0.f;
}

// ---------------- CSR build ----------------
__global__ __launch_bounds__(1024) void k_scan(const int* __restrict__ deg,
                                               int* __restrict__ rowptr,
                                               int* __restrict__ cursor,
                                               int N, int Etot) {
  __shared__ int wsum[16];
  __shared__ int s_carry;
  int tid = threadIdx.x, lane = tid & 63, w = tid >> 6;
  if (tid == 0) { s_carry = 0; rowptr[N] = Etot; }
  __syncthreads();
  for (int base = 0; base < N; base += 4096) {
    int i0 = base + tid * 4;
    int v[4];
    #pragma unroll
    for (int u = 0; u < 4; ++u) {
      int i = i0 + u;
      v[u] = (i < N) ? (deg[i] - 1) : 0;
    }
    int tsum = v[0] + v[1] + v[2] + v[3];
    int sc = tsum;
    #pragma unroll
    for (int off = 1; off < 64; off <<= 1) {
      int t = __shfl_up(sc, off);
      if (lane >= off) sc += t;
    }
    if (lane == 63) wsum[w] = sc;
    __syncthreads();
    if (w == 0 && lane < 16) {
      int xx = wsum[lane];
      #pragma unroll
      for (int off = 1; off < 16; off <<= 1) {
        int t = __shfl_up(xx, off);
        if (lane >= off) xx += t;
      }
      wsum[lane] = xx;
    }
    __syncthreads();
    int woff = (w == 0) ? 0 : wsum[w - 1];
    int excl = s_carry + woff + (sc - tsum);
    #pragma unroll
    for (int u = 0; u < 4; ++u) {
      int i = i0 + u;
      if (i < N) { rowptr[i] = excl; cursor[i] = excl; }
      excl += v[u];
    }
    __syncthreads();
    if (tid == 0) s_carry += wsum[15];
    __syncthreads();
  }
}

__global__ void k_fill(const int* __restrict__ src, const int* __restrict__ dst, int E,
                       int* __restrict__ cursor, int* __restrict__ csr_src) {
  int e = blockIdx.x * blockDim.x + threadIdx.x;
  if (e < E) {
    int d = dst[e];
    int pos = atomicAdd(&cursor[d], 1);
    csr_src[pos] = src[e];
  }
}

// ---------------- GEMM: C[m][n] = (sum_k A[m][k]*B[k][n]) * dis[m] ----------------
#define BM 128
#define BN 128
#define BK 16
__global__ __launch_bounds__(256) void k_gemm_scale(const float* __restrict__ A,
                                                    const float* __restrict__ B,
                                                    const float* __restrict__ dis,
                                                    float* __restrict__ C,
                                                    int M, int Nc, int K) {
  __shared__ float As[BK][BM];
  __shared__ float Bs[BK][BN];
  int tid = threadIdx.x;
  int block_row = blockIdx.x * BM;
  int block_col = blockIdx.y * BN;
  int tr = (tid >> 4) << 3;
  int tc = (tid & 15) << 3;
  float acc[8][8] = {};
  for (int k0 = 0; k0 < K; k0 += BK) {
    for (int t = tid; t < BM * BK / 4; t += 256) {
      int r = t >> 2;
      int cc = (t & 3) << 2;
      int gr = block_row + r;
      float4 v = {0.f, 0.f, 0.f, 0.f};
      if (gr < M) v = *(const float4*)(A + (size_t)gr * K + k0 + cc);
      As[cc + 0][r] = v.x; As[cc + 1][r] = v.y; As[cc + 2][r] = v.z; As[cc + 3][r] = v.w;
    }
    for (int t = tid; t < BK * BN / 4; t += 256) {
      int r = t >> 5;
      int cc = (t & 31) << 2;
      *(float4*)&Bs[r][cc] = *(const float4*)(B + (size_t)(k0 + r) * Nc + block_col + cc);
    }
    __syncthreads();
    #pragma unroll
    for (int k = 0; k < BK; ++k) {
      float a[8], b[8];
      *(float4*)&a[0] = *(const float4*)&As[k][tr];
      *(float4*)&a[4] = *(const float4*)&As[k][tr + 4];
      *(float4*)&b[0] = *(const float4*)&Bs[k][tc];
      *(float4*)&b[4] = *(const float4*)&Bs[k][tc + 4];
      #pragma unroll
      for (int i = 0; i < 8; ++i)
        #pragma unroll
        for (int j = 0; j < 8; ++j)
          acc[i][j] = fmaf(a[i], b[j], acc[i][j]);
    }
    __syncthreads();
  }
  for (int i = 0; i < 8; ++i) {
    int gr = block_row + tr + i;
    if (gr >= M) break;
    float s = dis[gr];
    for (int j = 0; j < 8; j += 4) {
      float4 v = {acc[i][j] * s, acc[i][j + 1] * s, acc[i][j + 2] * s, acc[i][j + 3] * s};
      *(float4*)(C + (size_t)gr * Nc + block_col + tc + j) = v;
    }
  }
}

// ---------------- sliced aggregation ----------------
// blockIdx.y = 16-channel slice (working set 3.2MB -> L2-resident).
// One wave per node; lane = sub*16 + c; each 16-lane group walks edges
// strided by 4; xor-reduce across groups at the end.
// out[i, col] = relu?(dis[i]*(sum_in hs[src,col] + hs[i,col]) + b[col])
template <int FCH>
__global__ __launch_bounds__(256) void k_agg_slice(const float* __restrict__ hs,
                                                   const int* __restrict__ rowptr,
                                                   const int* __restrict__ csr,
                                                   const float* __restrict__ dis,
                                                   const float* __restrict__ bias,
                                                   float* __restrict__ out,
                                                   int N, int do_relu) {
  int wid = threadIdx.x >> 6;
  int lane = threadIdx.x & 63;
  int node = blockIdx.x * 4 + wid;
  if (node >= N) return;
  int c = lane & 15;
  int sub = lane >> 4;
  int col = blockIdx.y * 16 + c;
  const float* base = hs + col;

  float acc = 0.f;
  int b0 = rowptr[node], e0 = rowptr[node + 1];
  int j = b0 + sub;
  for (; j + 12 < e0; j += 16) {
    int i0 = csr[j];
    int i1 = csr[j + 4];
    int i2 = csr[j + 8];
    int i3 = csr[j + 12];
    float v0 = base[(size_t)i0 * FCH];
    float v1 = base[(size_t)i1 * FCH];
    float v2 = base[(size_t)i2 * FCH];
    float v3 = base[(size_t)i3 * FCH];
    acc += v0 + v1 + v2 + v3;
  }
  for (; j < e0; j += 4) acc += base[(size_t)csr[j] * FCH];

  acc += __shfl_xor(acc, 16);
  acc += __shfl_xor(acc, 32);

  float self = base[(size_t)node * FCH];  // hs already scaled by dis[src]
  float r = (acc + self) * dis[node] + bias[col];
  if (do_relu) r = fmaxf(r, 0.f);
  if (lane < 16) out[(size_t)node * FCH + col] = r;
}

// ---------------- sliced decode ----------------
// blockIdx.y = 16-ch slice of z (128 ch -> 8 slices, 3.2MB each).
// Wave handles 16 edges (4 quads); lane = sub*16+c; partial dot over 16 ch,
// xor-reduce within the 16-lane group, atomicAdd into pre-zeroed out.
template <int FCH>
__global__ __launch_bounds__(256) void k_decode_slice(const float* __restrict__ z,
                                                      const int* __restrict__ src,
                                                      const int* __restrict__ dst,
                                                      float* __restrict__ out, int E) {
  int wid = threadIdx.x >> 6;
  int lane = threadIdx.x & 63;
  int c = lane & 15;
  int sub = lane >> 4;
  int e_base = (blockIdx.x * 4 + wid) * 16;
  if (e_base >= E) return;
  const float* zc = z + (size_t)blockIdx.y * 16 + c;

  float p[4];
  int ei[4];
  #pragma unroll
  for (int q = 0; q < 4; ++q) {
    int e = e_base + q * 4 + sub;
    ei[q] = e;
    p[q] = 0.f;
    if (e < E) {
      int a = src[e], b = dst[e];
      float za = zc[(size_t)a * FCH];
      float zb = zc[(size_t)b * FCH];
      p[q] = za * zb;
    }
  }
  #pragma unroll
  for (int q = 0; q < 4; ++q) {
    p[q] += __shfl_xor(p[q], 1);
    p[q] += __shfl_xor(p[q], 2);
    p[q] += __shfl_xor(p[q], 4);
    p[q] += __shfl_xor(p[q], 8);
    if (c == 0 && ei[q] < E) atomicAdd(out + ei[q], p[q]);
  }
}

extern "C" void kernel_launch(void* const* d_in, const int* in_sizes, int n_in,
                              void* d_out, int out_size, void* d_ws, size_t ws_size,
                              hipStream_t stream) {
  const float* x  = (const float*)d_in[0];
  const int* eidx = (const int*)d_in[1];
  const float* W1 = (const float*)d_in[2];
  const float* b1 = (const float*)d_in[3];
  const float* W2 = (const float*)d_in[4];
  const float* b2 = (const float*)d_in[5];
  float* out = (float*)d_out;

  const int IN_CH = 256, HID = 256, OUT_CH = 128;
  const int N = in_sizes[0] / IN_CH;
  const int E = in_sizes[1] / 2;
  const int* esrc = eidx;
  const int* edst = eidx + E;

  char* p = (char*)d_ws;
  auto alloc = [&](size_t bytes) -> char* { char* r = p; p += WS_ALIGN(bytes); return r; };
  int*   deg    = (int*)  alloc(sizeof(int) * N);
  float* dis    = (float*)alloc(sizeof(float) * N);
  int*   rowptr = (int*)  alloc(sizeof(int) * (N + 1));
  int*   cursor = (int*)  alloc(sizeof(int) * N);
  int*   csr    = (int*)  alloc(sizeof(int) * (size_t)E);
  float* bufA   = (float*)alloc(sizeof(float) * (size_t)N * HID);  // h1s, then h2s
  float* bufB   = (float*)alloc(sizeof(float) * (size_t)N * HID);  // z1, then z2

  const int T = 256;
  hipLaunchKernelGGL(k_init_deg, dim3((N + T - 1) / T), dim3(T), 0, stream, deg, N);
  hipLaunchKernelGGL(k_count, dim3((E + T - 1) / T), dim3(T), 0, stream, edst, E, deg);
  hipLaunchKernelGGL(k_dis, dim3((N + T - 1) / T), dim3(T), 0, stream, deg, dis, N);
  hipLaunchKernelGGL(k_scan, dim3(1), dim3(1024), 0, stream, deg, rowptr, cursor, N, E);
  hipLaunchKernelGGL(k_fill, dim3((E + T - 1) / T), dim3(T), 0, stream, esrc, edst, E, cursor, csr);
  hipLaunchKernelGGL(k_zero, dim3((E + T - 1) / T), dim3(T), 0, stream, out, E);

  // conv1: h1s = (x @ W1) * dis[row]; z1 = relu(dis*(sum+self)+b1)
  dim3 g1((N + BM - 1) / BM, HID / BN);
  hipLaunchKernelGGL(k_gemm_scale, g1, dim3(256), 0, stream, x, W1, dis, bufA, N, HID, IN_CH);
  hipLaunchKernelGGL((k_agg_slice<256>), dim3((N + 3) / 4, HID / 16), dim3(256), 0, stream,
                     bufA, rowptr, csr, dis, b1, bufB, N, 1);

  // conv2: h2s = (z1 @ W2) * dis[row]; z2 = dis*(sum+self)+b2
  dim3 g2((N + BM - 1) / BM, OUT_CH / BN);
  hipLaunchKernelGGL(k_gemm_scale, g2, dim3(256), 0, stream, bufB, W2, dis, bufA, N, OUT_CH, HID);
  hipLaunchKernelGGL((k_agg_slice<128>), dim3((N + 3) / 4, OUT_CH / 16), dim3(256), 0, stream,
                     bufA, rowptr, csr, dis, b2, bufB, N, 0);

  // decode: sliced partial dots accumulated into out
  int nwaves = (E + 15) / 16;
  hipLaunchKernelGGL((k_decode_slice<128>), dim3((nwaves + 3) / 4, OUT_CH / 16), dim3(256), 0, stream,
                     bufB, esrc, edst, out, E);
}

// Round 4
// 1288.262 us; speedup vs baseline: 1.0822x; 1.0822x over previous
//
#include <hip/hip_runtime.h>

#define WS_ALIGN(x) (((x) + 255) & ~(size_t)255)

// ---------------- degree / norm ----------------
__global__ void k_init_deg(int* deg, int N) {
  int i = blockIdx.x * blockDim.x + threadIdx.x;
  if (i < N) deg[i] = 1;  // self-loop
}

__global__ void k_count(const int* __restrict__ dst, int E, int* __restrict__ deg) {
  int e = blockIdx.x * blockDim.x + threadIdx.x;
  if (e < E) atomicAdd(&deg[dst[e]], 1);
}

__global__ void k_dis(const int* __restrict__ deg, float* __restrict__ dis, int N) {
  int i = blockIdx.x * blockDim.x + threadIdx.x;
  if (i < N) dis[i] = rsqrtf((float)deg[i]);
}

__global__ void k_zero(float* __restrict__ p, int n) {
  int i = blockIdx.x * blockDim.x + threadIdx.x;
  if (i < n) p[i] = 0.f;
}

// ---------------- CSR build ----------------
__global__ __launch_bounds__(1024) void k_scan(const int* __restrict__ deg,
                                               int* __restrict__ rowptr,
                                               int* __restrict__ cursor,
                                               int N, int Etot) {
  __shared__ int wsum[16];
  __shared__ int s_carry;
  int tid = threadIdx.x, lane = tid & 63, w = tid >> 6;
  if (tid == 0) { s_carry = 0; rowptr[N] = Etot; }
  __syncthreads();
  for (int base = 0; base < N; base += 4096) {
    int i0 = base + tid * 4;
    int v[4];
    #pragma unroll
    for (int u = 0; u < 4; ++u) {
      int i = i0 + u;
      v[u] = (i < N) ? (deg[i] - 1) : 0;
    }
    int tsum = v[0] + v[1] + v[2] + v[3];
    int sc = tsum;
    #pragma unroll
    for (int off = 1; off < 64; off <<= 1) {
      int t = __shfl_up(sc, off);
      if (lane >= off) sc += t;
    }
    if (lane == 63) wsum[w] = sc;
    __syncthreads();
    if (w == 0 && lane < 16) {
      int xx = wsum[lane];
      #pragma unroll
      for (int off = 1; off < 16; off <<= 1) {
        int t = __shfl_up(xx, off);
        if (lane >= off) xx += t;
      }
      wsum[lane] = xx;
    }
    __syncthreads();
    int woff = (w == 0) ? 0 : wsum[w - 1];
    int excl = s_carry + woff + (sc - tsum);
    #pragma unroll
    for (int u = 0; u < 4; ++u) {
      int i = i0 + u;
      if (i < N) { rowptr[i] = excl; cursor[i] = excl; }
      excl += v[u];
    }
    __syncthreads();
    if (tid == 0) s_carry += wsum[15];
    __syncthreads();
  }
}

__global__ void k_fill(const int* __restrict__ src, const int* __restrict__ dst, int E,
                       int* __restrict__ cursor, int* __restrict__ csr_src) {
  int e = blockIdx.x * blockDim.x + threadIdx.x;
  if (e < E) {
    int d = dst[e];
    int pos = atomicAdd(&cursor[d], 1);
    csr_src[pos] = src[e];
  }
}

// ---------------- GEMM: writes C in SLICE-MAJOR: C[(col/16)*M + row][col%16] ----------------
// C[m][n] = (sum_k A[m][k]*B[k][n]) * dis[m]
#define BM 128
#define BN 128
#define BK 16
__global__ __launch_bounds__(256) void k_gemm_scale_sm(const float* __restrict__ A,
                                                       const float* __restrict__ B,
                                                       const float* __restrict__ dis,
                                                       float* __restrict__ C,
                                                       int M, int Nc, int K) {
  __shared__ float As[BK][BM];
  __shared__ float Bs[BK][BN];
  int tid = threadIdx.x;
  int block_row = blockIdx.x * BM;
  int block_col = blockIdx.y * BN;
  int tr = (tid >> 4) << 3;
  int tc = (tid & 15) << 3;
  float acc[8][8] = {};
  for (int k0 = 0; k0 < K; k0 += BK) {
    for (int t = tid; t < BM * BK / 4; t += 256) {
      int r = t >> 2;
      int cc = (t & 3) << 2;
      int gr = block_row + r;
      float4 v = {0.f, 0.f, 0.f, 0.f};
      if (gr < M) v = *(const float4*)(A + (size_t)gr * K + k0 + cc);
      As[cc + 0][r] = v.x; As[cc + 1][r] = v.y; As[cc + 2][r] = v.z; As[cc + 3][r] = v.w;
    }
    for (int t = tid; t < BK * BN / 4; t += 256) {
      int r = t >> 5;
      int cc = (t & 31) << 2;
      *(float4*)&Bs[r][cc] = *(const float4*)(B + (size_t)(k0 + r) * Nc + block_col + cc);
    }
    __syncthreads();
    #pragma unroll
    for (int k = 0; k < BK; ++k) {
      float a[8], b[8];
      *(float4*)&a[0] = *(const float4*)&As[k][tr];
      *(float4*)&a[4] = *(const float4*)&As[k][tr + 4];
      *(float4*)&b[0] = *(const float4*)&Bs[k][tc];
      *(float4*)&b[4] = *(const float4*)&Bs[k][tc + 4];
      #pragma unroll
      for (int i = 0; i < 8; ++i)
        #pragma unroll
        for (int j = 0; j < 8; ++j)
          acc[i][j] = fmaf(a[i], b[j], acc[i][j]);
    }
    __syncthreads();
  }
  int col0 = block_col + tc;                 // multiple of 8
  size_t base = ((size_t)(col0 >> 4) * M) * 16 + (col0 & 15);
  for (int i = 0; i < 8; ++i) {
    int gr = block_row + tr + i;
    if (gr >= M) break;
    float s = dis[gr];
    float4 v0 = {acc[i][0] * s, acc[i][1] * s, acc[i][2] * s, acc[i][3] * s};
    float4 v1 = {acc[i][4] * s, acc[i][5] * s, acc[i][6] * s, acc[i][7] * s};
    float* cp = C + base + (size_t)gr * 16;
    *(float4*)cp = v0;
    *(float4*)(cp + 4) = v1;
  }
}

// ---------------- sliced aggregation (slice-major input) ----------------
// in  : [Nslices][N][16] slice-major (already scaled by dis[src])
// out : row-major [N][FCH] if !OUTSLICE, else slice-major [Nslices][N][16]
// out[i,col] = relu?(dis[i]*(sum_in in[src] + in[i]) + b[col])
template <int FCH, bool OUTSLICE>
__global__ __launch_bounds__(256) void k_agg_slice(const float* __restrict__ hs,
                                                   const int* __restrict__ rowptr,
                                                   const int* __restrict__ csr,
                                                   const float* __restrict__ dis,
                                                   const float* __restrict__ bias,
                                                   float* __restrict__ out,
                                                   int N, int do_relu) {
  int wid = threadIdx.x >> 6;
  int lane = threadIdx.x & 63;
  int node = blockIdx.x * 4 + wid;
  if (node >= N) return;
  int c = lane & 15;
  int sub = lane >> 4;
  const float* in = hs + (size_t)blockIdx.y * N * 16;

  float acc = 0.f;
  int b0 = rowptr[node], e0 = rowptr[node + 1];
  int j = b0 + sub;
  for (; j + 12 < e0; j += 16) {
    int i0 = csr[j];
    int i1 = csr[j + 4];
    int i2 = csr[j + 8];
    int i3 = csr[j + 12];
    float v0 = in[(i0 << 4) + c];
    float v1 = in[(i1 << 4) + c];
    float v2 = in[(i2 << 4) + c];
    float v3 = in[(i3 << 4) + c];
    acc += v0 + v1 + v2 + v3;
  }
  for (; j < e0; j += 4) acc += in[(csr[j] << 4) + c];

  acc += __shfl_xor(acc, 16);
  acc += __shfl_xor(acc, 32);

  float self = in[(node << 4) + c];
  int col = blockIdx.y * 16 + c;
  float r = (acc + self) * dis[node] + bias[col];
  if (do_relu) r = fmaxf(r, 0.f);
  if (lane < 16) {
    if (OUTSLICE)
      out[(size_t)blockIdx.y * N * 16 + (node << 4) + c] = r;
    else
      out[(size_t)node * FCH + col] = r;
  }
}

// ---------------- sliced decode (slice-major z) ----------------
// z : [8][N][16] slice-major. Wave = 16 edges (4 quads x 4 sub).
template <int FCH>
__global__ __launch_bounds__(256) void k_decode_slice(const float* __restrict__ z,
                                                      const int* __restrict__ src,
                                                      const int* __restrict__ dst,
                                                      float* __restrict__ out, int E, int N) {
  int wid = threadIdx.x >> 6;
  int lane = threadIdx.x & 63;
  int c = lane & 15;
  int sub = lane >> 4;
  int e_base = (blockIdx.x * 4 + wid) * 16;
  if (e_base >= E) return;
  const float* zc = z + (size_t)blockIdx.y * N * 16;

  float p[4];
  int ei[4];
  #pragma unroll
  for (int q = 0; q < 4; ++q) {
    int e = e_base + q * 4 + sub;
    ei[q] = e;
    p[q] = 0.f;
    if (e < E) {
      int a = src[e], b = dst[e];
      float za = zc[(a << 4) + c];
      float zb = zc[(b << 4) + c];
      p[q] = za * zb;
    }
  }
  #pragma unroll
  for (int q = 0; q < 4; ++q) {
    p[q] += __shfl_xor(p[q], 1);
    p[q] += __shfl_xor(p[q], 2);
    p[q] += __shfl_xor(p[q], 4);
    p[q] += __shfl_xor(p[q], 8);
    if (c == 0 && ei[q] < E) atomicAdd(out + ei[q], p[q]);
  }
}

extern "C" void kernel_launch(void* const* d_in, const int* in_sizes, int n_in,
                              void* d_out, int out_size, void* d_ws, size_t ws_size,
                              hipStream_t stream) {
  const float* x  = (const float*)d_in[0];
  const int* eidx = (const int*)d_in[1];
  const float* W1 = (const float*)d_in[2];
  const float* b1 = (const float*)d_in[3];
  const float* W2 = (const float*)d_in[4];
  const float* b2 = (const float*)d_in[5];
  float* out = (float*)d_out;

  const int IN_CH = 256, HID = 256, OUT_CH = 128;
  const int N = in_sizes[0] / IN_CH;
  const int E = in_sizes[1] / 2;
  const int* esrc = eidx;
  const int* edst = eidx + E;

  char* p = (char*)d_ws;
  auto alloc = [&](size_t bytes) -> char* { char* r = p; p += WS_ALIGN(bytes); return r; };
  int*   deg    = (int*)  alloc(sizeof(int) * N);
  float* dis    = (float*)alloc(sizeof(float) * N);
  int*   rowptr = (int*)  alloc(sizeof(int) * (N + 1));
  int*   cursor = (int*)  alloc(sizeof(int) * N);
  int*   csr    = (int*)  alloc(sizeof(int) * (size_t)E);
  float* bufA   = (float*)alloc(sizeof(float) * (size_t)N * HID);  // h1s / h2s (slice-major)
  float* bufB   = (float*)alloc(sizeof(float) * (size_t)N * HID);  // z1 (row-major) / z2 (slice-major)

  const int T = 256;
  hipLaunchKernelGGL(k_init_deg, dim3((N + T - 1) / T), dim3(T), 0, stream, deg, N);
  hipLaunchKernelGGL(k_count, dim3((E + T - 1) / T), dim3(T), 0, stream, edst, E, deg);
  hipLaunchKernelGGL(k_dis, dim3((N + T - 1) / T), dim3(T), 0, stream, deg, dis, N);
  hipLaunchKernelGGL(k_scan, dim3(1), dim3(1024), 0, stream, deg, rowptr, cursor, N, E);
  hipLaunchKernelGGL(k_fill, dim3((E + T - 1) / T), dim3(T), 0, stream, esrc, edst, E, cursor, csr);
  hipLaunchKernelGGL(k_zero, dim3((E + T - 1) / T), dim3(T), 0, stream, out, E);

  // conv1: h1s = (x @ W1)*dis[row] in slice-major; z1 = relu(...) row-major
  dim3 g1((N + BM - 1) / BM, HID / BN);
  hipLaunchKernelGGL(k_gemm_scale_sm, g1, dim3(256), 0, stream, x, W1, dis, bufA, N, HID, IN_CH);
  hipLaunchKernelGGL((k_agg_slice<256, false>), dim3((N + 3) / 4, HID / 16), dim3(256), 0, stream,
                     bufA, rowptr, csr, dis, b1, bufB, N, 1);

  // conv2: h2s = (z1 @ W2)*dis[row] slice-major; z2 slice-major
  dim3 g2((N + BM - 1) / BM, OUT_CH / BN);
  hipLaunchKernelGGL(k_gemm_scale_sm, g2, dim3(256), 0, stream, bufB, W2, dis, bufA, N, OUT_CH, HID);
  hipLaunchKernelGGL((k_agg_slice<128, true>), dim3((N + 3) / 4, OUT_CH / 16), dim3(256), 0, stream,
                     bufA, rowptr, csr, dis, b2, bufB, N, 0);

  // decode: sliced partial dots accumulated into out (pre-zeroed)
  int nwaves = (E + 15) / 16;
  hipLaunchKernelGGL((k_decode_slice<128>), dim3((nwaves + 3) / 4, OUT_CH / 16), dim3(256), 0, stream,
                     bufB, esrc, edst, out, E, N);
}

// Round 5
// 1003.643 us; speedup vs baseline: 1.3891x; 1.2836x over previous
//
#include <hip/hip_runtime.h>

#define WS_ALIGN(x) (((x) + 255) & ~(size_t)255)

// ---------------- degree / norm ----------------
__global__ void k_init_deg(int* deg, int N) {
  int i = blockIdx.x * blockDim.x + threadIdx.x;
  if (i < N) deg[i] = 1;  // self-loop
}

__global__ void k_count(const int* __restrict__ dst, int E, int* __restrict__ deg) {
  int e = blockIdx.x * blockDim.x + threadIdx.x;
  if (e < E) atomicAdd(&deg[dst[e]], 1);
}

__global__ void k_dis(const int* __restrict__ deg, float* __restrict__ dis, int N) {
  int i = blockIdx.x * blockDim.x + threadIdx.x;
  if (i < N) dis[i] = rsqrtf((float)deg[i]);
}

__global__ void k_zero(float* __restrict__ p, int n) {
  int i = blockIdx.x * blockDim.x + threadIdx.x;
  if (i < n) p[i] = 0.f;
}

// ---------------- CSR build ----------------
__global__ __launch_bounds__(1024) void k_scan(const int* __restrict__ deg,
                                               int* __restrict__ rowptr,
                                               int* __restrict__ cursor,
                                               int N, int Etot) {
  __shared__ int wsum[16];
  __shared__ int s_carry;
  int tid = threadIdx.x, lane = tid & 63, w = tid >> 6;
  if (tid == 0) { s_carry = 0; rowptr[N] = Etot; }
  __syncthreads();
  for (int base = 0; base < N; base += 4096) {
    int i0 = base + tid * 4;
    int v[4];
    #pragma unroll
    for (int u = 0; u < 4; ++u) {
      int i = i0 + u;
      v[u] = (i < N) ? (deg[i] - 1) : 0;
    }
    int tsum = v[0] + v[1] + v[2] + v[3];
    int sc = tsum;
    #pragma unroll
    for (int off = 1; off < 64; off <<= 1) {
      int t = __shfl_up(sc, off);
      if (lane >= off) sc += t;
    }
    if (lane == 63) wsum[w] = sc;
    __syncthreads();
    if (w == 0 && lane < 16) {
      int xx = wsum[lane];
      #pragma unroll
      for (int off = 1; off < 16; off <<= 1) {
        int t = __shfl_up(xx, off);
        if (lane >= off) xx += t;
      }
      wsum[lane] = xx;
    }
    __syncthreads();
    int woff = (w == 0) ? 0 : wsum[w - 1];
    int excl = s_carry + woff + (sc - tsum);
    #pragma unroll
    for (int u = 0; u < 4; ++u) {
      int i = i0 + u;
      if (i < N) { rowptr[i] = excl; cursor[i] = excl; }
      excl += v[u];
    }
    __syncthreads();
    if (tid == 0) s_carry += wsum[15];
    __syncthreads();
  }
}

__global__ void k_fill(const int* __restrict__ src, const int* __restrict__ dst, int E,
                       int* __restrict__ cursor, int* __restrict__ csr_src) {
  int e = blockIdx.x * blockDim.x + threadIdx.x;
  if (e < E) {
    int d = dst[e];
    int pos = atomicAdd(&cursor[d], 1);
    csr_src[pos] = src[e];
  }
}

// ---------------- GEMM: writes C in SLICE-MAJOR: C[(col/16)*M + row][col%16] ----------------
// C[m][n] = (sum_k A[m][k]*B[k][n]) * dis[m]
#define BM 128
#define BN 128
#define BK 16
__global__ __launch_bounds__(256) void k_gemm_scale_sm(const float* __restrict__ A,
                                                       const float* __restrict__ B,
                                                       const float* __restrict__ dis,
                                                       float* __restrict__ C,
                                                       int M, int Nc, int K) {
  __shared__ float As[BK][BM];
  __shared__ float Bs[BK][BN];
  int tid = threadIdx.x;
  int block_row = blockIdx.x * BM;
  int block_col = blockIdx.y * BN;
  int tr = (tid >> 4) << 3;
  int tc = (tid & 15) << 3;
  float acc[8][8] = {};
  for (int k0 = 0; k0 < K; k0 += BK) {
    for (int t = tid; t < BM * BK / 4; t += 256) {
      int r = t >> 2;
      int cc = (t & 3) << 2;
      int gr = block_row + r;
      float4 v = {0.f, 0.f, 0.f, 0.f};
      if (gr < M) v = *(const float4*)(A + (size_t)gr * K + k0 + cc);
      As[cc + 0][r] = v.x; As[cc + 1][r] = v.y; As[cc + 2][r] = v.z; As[cc + 3][r] = v.w;
    }
    for (int t = tid; t < BK * BN / 4; t += 256) {
      int r = t >> 5;
      int cc = (t & 31) << 2;
      *(float4*)&Bs[r][cc] = *(const float4*)(B + (size_t)(k0 + r) * Nc + block_col + cc);
    }
    __syncthreads();
    #pragma unroll
    for (int k = 0; k < BK; ++k) {
      float a[8], b[8];
      *(float4*)&a[0] = *(const float4*)&As[k][tr];
      *(float4*)&a[4] = *(const float4*)&As[k][tr + 4];
      *(float4*)&b[0] = *(const float4*)&Bs[k][tc];
      *(float4*)&b[4] = *(const float4*)&Bs[k][tc + 4];
      #pragma unroll
      for (int i = 0; i < 8; ++i)
        #pragma unroll
        for (int j = 0; j < 8; ++j)
          acc[i][j] = fmaf(a[i], b[j], acc[i][j]);
    }
    __syncthreads();
  }
  int col0 = block_col + tc;                 // multiple of 8
  size_t base = ((size_t)(col0 >> 4) * M) * 16 + (col0 & 15);
  for (int i = 0; i < 8; ++i) {
    int gr = block_row + tr + i;
    if (gr >= M) break;
    float s = dis[gr];
    float4 v0 = {acc[i][0] * s, acc[i][1] * s, acc[i][2] * s, acc[i][3] * s};
    float4 v1 = {acc[i][4] * s, acc[i][5] * s, acc[i][6] * s, acc[i][7] * s};
    float* cp = C + base + (size_t)gr * 16;
    *(float4*)cp = v0;
    *(float4*)(cp + 4) = v1;
  }
}

// ---------------- sliced aggregation, float4 lanes ----------------
// in : [Nslices][N][16] slice-major (already scaled by dis[src]).
// lane: c2 = lane&3 -> float4 chunk of the 16 channels; sub = lane>>2 -> edge stride 16.
// One wave per (node, slice). out row-major [N][FCH] or slice-major.
template <int FCH, bool OUTSLICE>
__global__ __launch_bounds__(256) void k_agg_slice4(const float* __restrict__ hs,
                                                    const int* __restrict__ rowptr,
                                                    const int* __restrict__ csr,
                                                    const float* __restrict__ dis,
                                                    const float* __restrict__ bias,
                                                    float* __restrict__ out,
                                                    int N, int do_relu) {
  int wid = threadIdx.x >> 6;
  int lane = threadIdx.x & 63;
  int node = blockIdx.x * 4 + wid;
  if (node >= N) return;
  int c2 = lane & 3;
  int sub = lane >> 2;
  const float* in = hs + (size_t)blockIdx.y * N * 16;

  float4 acc = {0.f, 0.f, 0.f, 0.f};
  int b0 = rowptr[node], e0 = rowptr[node + 1];
  for (int j = b0 + sub; j < e0; j += 16) {
    int idx = csr[j];
    float4 v = *(const float4*)(in + ((size_t)idx << 4) + (c2 << 2));
    acc.x += v.x; acc.y += v.y; acc.z += v.z; acc.w += v.w;
  }
  #pragma unroll
  for (int m = 4; m <= 32; m <<= 1) {
    acc.x += __shfl_xor(acc.x, m);
    acc.y += __shfl_xor(acc.y, m);
    acc.z += __shfl_xor(acc.z, m);
    acc.w += __shfl_xor(acc.w, m);
  }
  if (sub == 0) {
    float4 self = *(const float4*)(in + ((size_t)node << 4) + (c2 << 2));
    float dn = dis[node];
    int col = blockIdx.y * 16 + (c2 << 2);
    float4 bv = *(const float4*)(bias + col);
    float4 r;
    r.x = (acc.x + self.x) * dn + bv.x;
    r.y = (acc.y + self.y) * dn + bv.y;
    r.z = (acc.z + self.z) * dn + bv.z;
    r.w = (acc.w + self.w) * dn + bv.w;
    if (do_relu) {
      r.x = fmaxf(r.x, 0.f); r.y = fmaxf(r.y, 0.f);
      r.z = fmaxf(r.z, 0.f); r.w = fmaxf(r.w, 0.f);
    }
    if (OUTSLICE)
      *(float4*)(out + (size_t)blockIdx.y * N * 16 + ((size_t)node << 4) + (c2 << 2)) = r;
    else
      *(float4*)(out + (size_t)node * FCH + col) = r;
  }
}

// ---------------- sliced decode, float4 lanes ----------------
// z : [8][N][16] slice-major. Wave = 16 edges; 4 lanes per edge (c2 float4 chunks).
__global__ __launch_bounds__(256) void k_decode_slice4(const float* __restrict__ z,
                                                       const int* __restrict__ src,
                                                       const int* __restrict__ dst,
                                                       float* __restrict__ out, int E, int N) {
  int wid = threadIdx.x >> 6;
  int lane = threadIdx.x & 63;
  int c2 = lane & 3;
  int sub = lane >> 2;
  int e = (blockIdx.x * 4 + wid) * 16 + sub;
  if (e >= E) return;  // whole 4-lane group exits together (same e)
  const float* zc = z + (size_t)blockIdx.y * N * 16;
  int a = src[e], b = dst[e];
  float4 za = *(const float4*)(zc + ((size_t)a << 4) + (c2 << 2));
  float4 zb = *(const float4*)(zc + ((size_t)b << 4) + (c2 << 2));
  float p = za.x * zb.x + za.y * zb.y + za.z * zb.z + za.w * zb.w;
  p += __shfl_xor(p, 1);
  p += __shfl_xor(p, 2);
  if (c2 == 0) atomicAdd(out + e, p);
}

extern "C" void kernel_launch(void* const* d_in, const int* in_sizes, int n_in,
                              void* d_out, int out_size, void* d_ws, size_t ws_size,
                              hipStream_t stream) {
  const float* x  = (const float*)d_in[0];
  const int* eidx = (const int*)d_in[1];
  const float* W1 = (const float*)d_in[2];
  const float* b1 = (const float*)d_in[3];
  const float* W2 = (const float*)d_in[4];
  const float* b2 = (const float*)d_in[5];
  float* out = (float*)d_out;

  const int IN_CH = 256, HID = 256, OUT_CH = 128;
  const int N = in_sizes[0] / IN_CH;
  const int E = in_sizes[1] / 2;
  const int* esrc = eidx;
  const int* edst = eidx + E;

  char* p = (char*)d_ws;
  auto alloc = [&](size_t bytes) -> char* { char* r = p; p += WS_ALIGN(bytes); return r; };
  int*   deg    = (int*)  alloc(sizeof(int) * N);
  float* dis    = (float*)alloc(sizeof(float) * N);
  int*   rowptr = (int*)  alloc(sizeof(int) * (N + 1));
  int*   cursor = (int*)  alloc(sizeof(int) * N);
  int*   csr    = (int*)  alloc(sizeof(int) * (size_t)E);
  float* bufA   = (float*)alloc(sizeof(float) * (size_t)N * HID);  // h1s / h2s (slice-major)
  float* bufB   = (float*)alloc(sizeof(float) * (size_t)N * HID);  // z1 (row-major) / z2 (slice-major)

  const int T = 256;
  hipLaunchKernelGGL(k_init_deg, dim3((N + T - 1) / T), dim3(T), 0, stream, deg, N);
  hipLaunchKernelGGL(k_count, dim3((E + T - 1) / T), dim3(T), 0, stream, edst, E, deg);
  hipLaunchKernelGGL(k_dis, dim3((N + T - 1) / T), dim3(T), 0, stream, deg, dis, N);
  hipLaunchKernelGGL(k_scan, dim3(1), dim3(1024), 0, stream, deg, rowptr, cursor, N, E);
  hipLaunchKernelGGL(k_fill, dim3((E + T - 1) / T), dim3(T), 0, stream, esrc, edst, E, cursor, csr);
  hipLaunchKernelGGL(k_zero, dim3((E + T - 1) / T), dim3(T), 0, stream, out, E);

  // conv1: h1s = (x @ W1)*dis[row] slice-major; z1 = relu(...) row-major
  dim3 g1((N + BM - 1) / BM, HID / BN);
  hipLaunchKernelGGL(k_gemm_scale_sm, g1, dim3(256), 0, stream, x, W1, dis, bufA, N, HID, IN_CH);
  hipLaunchKernelGGL((k_agg_slice4<256, false>), dim3((N + 3) / 4, HID / 16), dim3(256), 0, stream,
                     bufA, rowptr, csr, dis, b1, bufB, N, 1);

  // conv2: h2s = (z1 @ W2)*dis[row] slice-major; z2 slice-major
  dim3 g2((N + BM - 1) / BM, OUT_CH / BN);
  hipLaunchKernelGGL(k_gemm_scale_sm, g2, dim3(256), 0, stream, bufB, W2, dis, bufA, N, OUT_CH, HID);
  hipLaunchKernelGGL((k_agg_slice4<128, true>), dim3((N + 3) / 4, OUT_CH / 16), dim3(256), 0, stream,
                     bufA, rowptr, csr, dis, b2, bufB, N, 0);

  // decode: sliced partial dots accumulated into out (pre-zeroed)
  hipLaunchKernelGGL(k_decode_slice4, dim3((E + 63) / 64, OUT_CH / 16), dim3(256), 0, stream,
                     bufB, esrc, edst, out, E, N);
}

// Round 6
// 992.971 us; speedup vs baseline: 1.4040x; 1.0107x over previous
//
#include <hip/hip_runtime.h>

#define WS_ALIGN(x) (((x) + 255) & ~(size_t)255)

// ---------------- degree / norm ----------------
__global__ void k_init_deg(int* deg, int N) {
  int i = blockIdx.x * blockDim.x + threadIdx.x;
  if (i < N) deg[i] = 1;  // self-loop
}

__global__ void k_count(const int* __restrict__ dst, int E, int* __restrict__ deg) {
  int e = blockIdx.x * blockDim.x + threadIdx.x;
  if (e < E) atomicAdd(&deg[dst[e]], 1);
}

__global__ void k_dis(const int* __restrict__ deg, float* __restrict__ dis, int N) {
  int i = blockIdx.x * blockDim.x + threadIdx.x;
  if (i < N) dis[i] = rsqrtf((float)deg[i]);
}

__global__ void k_zero(float* __restrict__ p, int n) {
  int i = blockIdx.x * blockDim.x + threadIdx.x;
  if (i < n) p[i] = 0.f;
}

// ---------------- CSR build ----------------
__global__ __launch_bounds__(1024) void k_scan(const int* __restrict__ deg,
                                               int* __restrict__ rowptr,
                                               int* __restrict__ cursor,
                                               int N, int Etot) {
  __shared__ int wsum[16];
  __shared__ int s_carry;
  int tid = threadIdx.x, lane = tid & 63, w = tid >> 6;
  if (tid == 0) { s_carry = 0; rowptr[N] = Etot; }
  __syncthreads();
  for (int base = 0; base < N; base += 4096) {
    int i0 = base + tid * 4;
    int v[4];
    #pragma unroll
    for (int u = 0; u < 4; ++u) {
      int i = i0 + u;
      v[u] = (i < N) ? (deg[i] - 1) : 0;
    }
    int tsum = v[0] + v[1] + v[2] + v[3];
    int sc = tsum;
    #pragma unroll
    for (int off = 1; off < 64; off <<= 1) {
      int t = __shfl_up(sc, off);
      if (lane >= off) sc += t;
    }
    if (lane == 63) wsum[w] = sc;
    __syncthreads();
    if (w == 0 && lane < 16) {
      int xx = wsum[lane];
      #pragma unroll
      for (int off = 1; off < 16; off <<= 1) {
        int t = __shfl_up(xx, off);
        if (lane >= off) xx += t;
      }
      wsum[lane] = xx;
    }
    __syncthreads();
    int woff = (w == 0) ? 0 : wsum[w - 1];
    int excl = s_carry + woff + (sc - tsum);
    #pragma unroll
    for (int u = 0; u < 4; ++u) {
      int i = i0 + u;
      if (i < N) { rowptr[i] = excl; cursor[i] = excl; }
      excl += v[u];
    }
    __syncthreads();
    if (tid == 0) s_carry += wsum[15];
    __syncthreads();
  }
}

__global__ void k_fill(const int* __restrict__ src, const int* __restrict__ dst, int E,
                       int* __restrict__ cursor, int* __restrict__ csr_src) {
  int e = blockIdx.x * blockDim.x + threadIdx.x;
  if (e < E) {
    int d = dst[e];
    int pos = atomicAdd(&cursor[d], 1);
    csr_src[pos] = src[e];
  }
}

// ---------------- GEMM: writes C in SLICE-MAJOR: C[(col/16)*M + row][col%16] ----------------
// C[m][n] = (sum_k A[m][k]*B[k][n]) * dis[m]
#define BM 128
#define BN 128
#define BK 16
__global__ __launch_bounds__(256) void k_gemm_scale_sm(const float* __restrict__ A,
                                                       const float* __restrict__ B,
                                                       const float* __restrict__ dis,
                                                       float* __restrict__ C,
                                                       int M, int Nc, int K) {
  __shared__ float As[BK][BM];
  __shared__ float Bs[BK][BN];
  int tid = threadIdx.x;
  int block_row = blockIdx.x * BM;
  int block_col = blockIdx.y * BN;
  int tr = (tid >> 4) << 3;
  int tc = (tid & 15) << 3;
  float acc[8][8] = {};
  for (int k0 = 0; k0 < K; k0 += BK) {
    for (int t = tid; t < BM * BK / 4; t += 256) {
      int r = t >> 2;
      int cc = (t & 3) << 2;
      int gr = block_row + r;
      float4 v = {0.f, 0.f, 0.f, 0.f};
      if (gr < M) v = *(const float4*)(A + (size_t)gr * K + k0 + cc);
      As[cc + 0][r] = v.x; As[cc + 1][r] = v.y; As[cc + 2][r] = v.z; As[cc + 3][r] = v.w;
    }
    for (int t = tid; t < BK * BN / 4; t += 256) {
      int r = t >> 5;
      int cc = (t & 31) << 2;
      *(float4*)&Bs[r][cc] = *(const float4*)(B + (size_t)(k0 + r) * Nc + block_col + cc);
    }
    __syncthreads();
    #pragma unroll
    for (int k = 0; k < BK; ++k) {
      float a[8], b[8];
      *(float4*)&a[0] = *(const float4*)&As[k][tr];
      *(float4*)&a[4] = *(const float4*)&As[k][tr + 4];
      *(float4*)&b[0] = *(const float4*)&Bs[k][tc];
      *(float4*)&b[4] = *(const float4*)&Bs[k][tc + 4];
      #pragma unroll
      for (int i = 0; i < 8; ++i)
        #pragma unroll
        for (int j = 0; j < 8; ++j)
          acc[i][j] = fmaf(a[i], b[j], acc[i][j]);
    }
    __syncthreads();
  }
  int col0 = block_col + tc;                 // multiple of 8
  size_t base = ((size_t)(col0 >> 4) * M) * 16 + (col0 & 15);
  for (int i = 0; i < 8; ++i) {
    int gr = block_row + tr + i;
    if (gr >= M) break;
    float s = dis[gr];
    float4 v0 = {acc[i][0] * s, acc[i][1] * s, acc[i][2] * s, acc[i][3] * s};
    float4 v1 = {acc[i][4] * s, acc[i][5] * s, acc[i][6] * s, acc[i][7] * s};
    float* cp = C + base + (size_t)gr * 16;
    *(float4*)cp = v0;
    *(float4*)(cp + 4) = v1;
  }
}

// ---------------- aggregation: 16 nodes/wave, serial edge walk, no reduction ----------------
// in : [Nslices][N][16] slice-major (already scaled by dis[src]).
// sub = lane>>2 owns node (node_base+sub); c2 = lane&3 owns float4 chunk.
// Batch-8 index+gather for MLP. out row-major [N][FCH] or slice-major.
template <int FCH, bool OUTSLICE>
__global__ __launch_bounds__(256) void k_agg_g16(const float* __restrict__ hs,
                                                 const int* __restrict__ rowptr,
                                                 const int* __restrict__ csr,
                                                 const float* __restrict__ dis,
                                                 const float* __restrict__ bias,
                                                 float* __restrict__ out,
                                                 int N, int do_relu) {
  int wid = threadIdx.x >> 6;
  int lane = threadIdx.x & 63;
  int sub = lane >> 2;
  int c2 = lane & 3;
  int node = (blockIdx.x * 4 + wid) * 16 + sub;
  const float* in = hs + (size_t)blockIdx.y * N * 16;
  bool valid = node < N;

  float4 acc = {0.f, 0.f, 0.f, 0.f};
  int b0 = 0, e0 = 0;
  if (valid) {
    b0 = rowptr[node];
    e0 = rowptr[node + 1];
    acc = *(const float4*)(in + ((size_t)node << 4) + (c2 << 2));  // self
  }
  int j = b0;
  for (; j + 8 <= e0; j += 8) {
    int i0 = csr[j];     int i1 = csr[j + 1];
    int i2 = csr[j + 2]; int i3 = csr[j + 3];
    int i4 = csr[j + 4]; int i5 = csr[j + 5];
    int i6 = csr[j + 6]; int i7 = csr[j + 7];
    float4 v0 = *(const float4*)(in + ((size_t)i0 << 4) + (c2 << 2));
    float4 v1 = *(const float4*)(in + ((size_t)i1 << 4) + (c2 << 2));
    float4 v2 = *(const float4*)(in + ((size_t)i2 << 4) + (c2 << 2));
    float4 v3 = *(const float4*)(in + ((size_t)i3 << 4) + (c2 << 2));
    float4 v4 = *(const float4*)(in + ((size_t)i4 << 4) + (c2 << 2));
    float4 v5 = *(const float4*)(in + ((size_t)i5 << 4) + (c2 << 2));
    float4 v6 = *(const float4*)(in + ((size_t)i6 << 4) + (c2 << 2));
    float4 v7 = *(const float4*)(in + ((size_t)i7 << 4) + (c2 << 2));
    acc.x += ((v0.x + v1.x) + (v2.x + v3.x)) + ((v4.x + v5.x) + (v6.x + v7.x));
    acc.y += ((v0.y + v1.y) + (v2.y + v3.y)) + ((v4.y + v5.y) + (v6.y + v7.y));
    acc.z += ((v0.z + v1.z) + (v2.z + v3.z)) + ((v4.z + v5.z) + (v6.z + v7.z));
    acc.w += ((v0.w + v1.w) + (v2.w + v3.w)) + ((v4.w + v5.w) + (v6.w + v7.w));
  }
  for (; j < e0; ++j) {
    int idx = csr[j];
    float4 v = *(const float4*)(in + ((size_t)idx << 4) + (c2 << 2));
    acc.x += v.x; acc.y += v.y; acc.z += v.z; acc.w += v.w;
  }
  if (valid) {
    float dn = dis[node];
    int col = blockIdx.y * 16 + (c2 << 2);
    float4 bv = *(const float4*)(bias + col);
    float4 r;
    r.x = acc.x * dn + bv.x;
    r.y = acc.y * dn + bv.y;
    r.z = acc.z * dn + bv.z;
    r.w = acc.w * dn + bv.w;
    if (do_relu) {
      r.x = fmaxf(r.x, 0.f); r.y = fmaxf(r.y, 0.f);
      r.z = fmaxf(r.z, 0.f); r.w = fmaxf(r.w, 0.f);
    }
    if (OUTSLICE)
      *(float4*)(out + (size_t)blockIdx.y * N * 16 + ((size_t)node << 4) + (c2 << 2)) = r;
    else
      *(float4*)(out + (size_t)node * FCH + col) = r;
  }
}

// ---------------- decode: one thread per (edge, slice) ----------------
// z : [8][N][16] slice-major. 8 independent 16B loads (2 L1 lines), dot in regs, one atomic.
__global__ __launch_bounds__(256) void k_decode_e(const float* __restrict__ z,
                                                  const int* __restrict__ src,
                                                  const int* __restrict__ dst,
                                                  float* __restrict__ out, int E, int N) {
  int e = blockIdx.x * 256 + threadIdx.x;
  if (e >= E) return;
  const float* zc = z + (size_t)blockIdx.y * N * 16;
  int a = src[e], b = dst[e];
  const float4* pa = (const float4*)(zc + ((size_t)a << 4));
  const float4* pb = (const float4*)(zc + ((size_t)b << 4));
  float4 a0 = pa[0], a1 = pa[1], a2 = pa[2], a3 = pa[3];
  float4 b0 = pb[0], b1 = pb[1], b2 = pb[2], b3 = pb[3];
  float p = a0.x * b0.x + a0.y * b0.y + a0.z * b0.z + a0.w * b0.w;
  p += a1.x * b1.x + a1.y * b1.y + a1.z * b1.z + a1.w * b1.w;
  p += a2.x * b2.x + a2.y * b2.y + a2.z * b2.z + a2.w * b2.w;
  p += a3.x * b3.x + a3.y * b3.y + a3.z * b3.z + a3.w * b3.w;
  atomicAdd(out + e, p);
}

extern "C" void kernel_launch(void* const* d_in, const int* in_sizes, int n_in,
                              void* d_out, int out_size, void* d_ws, size_t ws_size,
                              hipStream_t stream) {
  const float* x  = (const float*)d_in[0];
  const int* eidx = (const int*)d_in[1];
  const float* W1 = (const float*)d_in[2];
  const float* b1 = (const float*)d_in[3];
  const float* W2 = (const float*)d_in[4];
  const float* b2 = (const float*)d_in[5];
  float* out = (float*)d_out;

  const int IN_CH = 256, HID = 256, OUT_CH = 128;
  const int N = in_sizes[0] / IN_CH;
  const int E = in_sizes[1] / 2;
  const int* esrc = eidx;
  const int* edst = eidx + E;

  char* p = (char*)d_ws;
  auto alloc = [&](size_t bytes) -> char* { char* r = p; p += WS_ALIGN(bytes); return r; };
  int*   deg    = (int*)  alloc(sizeof(int) * N);
  float* dis    = (float*)alloc(sizeof(float) * N);
  int*   rowptr = (int*)  alloc(sizeof(int) * (N + 1));
  int*   cursor = (int*)  alloc(sizeof(int) * N);
  int*   csr    = (int*)  alloc(sizeof(int) * (size_t)E);
  float* bufA   = (float*)alloc(sizeof(float) * (size_t)N * HID);  // h1s / h2s (slice-major)
  float* bufB   = (float*)alloc(sizeof(float) * (size_t)N * HID);  // z1 (row-major) / z2 (slice-major)

  const int T = 256;
  hipLaunchKernelGGL(k_init_deg, dim3((N + T - 1) / T), dim3(T), 0, stream, deg, N);
  hipLaunchKernelGGL(k_count, dim3((E + T - 1) / T), dim3(T), 0, stream, edst, E, deg);
  hipLaunchKernelGGL(k_dis, dim3((N + T - 1) / T), dim3(T), 0, stream, deg, dis, N);
  hipLaunchKernelGGL(k_scan, dim3(1), dim3(1024), 0, stream, deg, rowptr, cursor, N, E);
  hipLaunchKernelGGL(k_fill, dim3((E + T - 1) / T), dim3(T), 0, stream, esrc, edst, E, cursor, csr);
  hipLaunchKernelGGL(k_zero, dim3((E + T - 1) / T), dim3(T), 0, stream, out, E);

  int ngrp = (N + 15) / 16;        // 16-node groups
  int gblk = (ngrp + 3) / 4;       // 4 waves per block

  // conv1: h1s = (x @ W1)*dis[row] slice-major; z1 = relu(...) row-major
  dim3 g1((N + BM - 1) / BM, HID / BN);
  hipLaunchKernelGGL(k_gemm_scale_sm, g1, dim3(256), 0, stream, x, W1, dis, bufA, N, HID, IN_CH);
  hipLaunchKernelGGL((k_agg_g16<256, false>), dim3(gblk, HID / 16), dim3(256), 0, stream,
                     bufA, rowptr, csr, dis, b1, bufB, N, 1);

  // conv2: h2s = (z1 @ W2)*dis[row] slice-major; z2 slice-major
  dim3 g2((N + BM - 1) / BM, OUT_CH / BN);
  hipLaunchKernelGGL(k_gemm_scale_sm, g2, dim3(256), 0, stream, bufB, W2, dis, bufA, N, OUT_CH, HID);
  hipLaunchKernelGGL((k_agg_g16<128, true>), dim3(gblk, OUT_CH / 16), dim3(256), 0, stream,
                     bufA, rowptr, csr, dis, b2, bufB, N, 0);

  // decode: one thread per (edge, slice), atomic into pre-zeroed out
  hipLaunchKernelGGL(k_decode_e, dim3((E + 255) / 256, OUT_CH / 16), dim3(256), 0, stream,
                     bufB, esrc, edst, out, E, N);
}

// Round 7
// 892.865 us; speedup vs baseline: 1.5614x; 1.1121x over previous
//
#include <hip/hip_runtime.h>

#define WS_ALIGN(x) (((x) + 255) & ~(size_t)255)

// ---------------- degree / norm ----------------
__global__ void k_init_deg(int* deg, int N) {
  int i = blockIdx.x * blockDim.x + threadIdx.x;
  if (i < N) deg[i] = 1;  // self-loop
}

__global__ void k_count(const int* __restrict__ dst, int E, int* __restrict__ deg) {
  int e = blockIdx.x * blockDim.x + threadIdx.x;
  if (e < E) atomicAdd(&deg[dst[e]], 1);
}

__global__ void k_dis(const int* __restrict__ deg, float* __restrict__ dis, int N) {
  int i = blockIdx.x * blockDim.x + threadIdx.x;
  if (i < N) dis[i] = rsqrtf((float)deg[i]);
}

// ---------------- CSR build ----------------
__global__ __launch_bounds__(1024) void k_scan(const int* __restrict__ deg,
                                               int* __restrict__ rowptr,
                                               int* __restrict__ cursor,
                                               int N, int Etot) {
  __shared__ int wsum[16];
  __shared__ int s_carry;
  int tid = threadIdx.x, lane = tid & 63, w = tid >> 6;
  if (tid == 0) { s_carry = 0; rowptr[N] = Etot; }
  __syncthreads();
  for (int base = 0; base < N; base += 4096) {
    int i0 = base + tid * 4;
    int v[4];
    #pragma unroll
    for (int u = 0; u < 4; ++u) {
      int i = i0 + u;
      v[u] = (i < N) ? (deg[i] - 1) : 0;
    }
    int tsum = v[0] + v[1] + v[2] + v[3];
    int sc = tsum;
    #pragma unroll
    for (int off = 1; off < 64; off <<= 1) {
      int t = __shfl_up(sc, off);
      if (lane >= off) sc += t;
    }
    if (lane == 63) wsum[w] = sc;
    __syncthreads();
    if (w == 0 && lane < 16) {
      int xx = wsum[lane];
      #pragma unroll
      for (int off = 1; off < 16; off <<= 1) {
        int t = __shfl_up(xx, off);
        if (lane >= off) xx += t;
      }
      wsum[lane] = xx;
    }
    __syncthreads();
    int woff = (w == 0) ? 0 : wsum[w - 1];
    int excl = s_carry + woff + (sc - tsum);
    #pragma unroll
    for (int u = 0; u < 4; ++u) {
      int i = i0 + u;
      if (i < N) { rowptr[i] = excl; cursor[i] = excl; }
      excl += v[u];
    }
    __syncthreads();
    if (tid == 0) s_carry += wsum[15];
    __syncthreads();
  }
}

__global__ void k_fill(const int* __restrict__ src, const int* __restrict__ dst, int E,
                       int* __restrict__ cursor, int* __restrict__ csr_src) {
  int e = blockIdx.x * blockDim.x + threadIdx.x;
  if (e < E) {
    int d = dst[e];
    int pos = atomicAdd(&cursor[d], 1);
    csr_src[pos] = src[e];
  }
}

// ---------------- GEMM: writes C in SLICE-MAJOR: C[(col/16)*M + row][col%16] ----------------
// C[m][n] = (sum_k A[m][k]*B[k][n]) * dis[m]
#define BM 128
#define BN 128
#define BK 16
__global__ __launch_bounds__(256) void k_gemm_scale_sm(const float* __restrict__ A,
                                                       const float* __restrict__ B,
                                                       const float* __restrict__ dis,
                                                       float* __restrict__ C,
                                                       int M, int Nc, int K) {
  __shared__ float As[BK][BM];
  __shared__ float Bs[BK][BN];
  int tid = threadIdx.x;
  int block_row = blockIdx.x * BM;
  int block_col = blockIdx.y * BN;
  int tr = (tid >> 4) << 3;
  int tc = (tid & 15) << 3;
  float acc[8][8] = {};
  for (int k0 = 0; k0 < K; k0 += BK) {
    for (int t = tid; t < BM * BK / 4; t += 256) {
      int r = t >> 2;
      int cc = (t & 3) << 2;
      int gr = block_row + r;
      float4 v = {0.f, 0.f, 0.f, 0.f};
      if (gr < M) v = *(const float4*)(A + (size_t)gr * K + k0 + cc);
      As[cc + 0][r] = v.x; As[cc + 1][r] = v.y; As[cc + 2][r] = v.z; As[cc + 3][r] = v.w;
    }
    for (int t = tid; t < BK * BN / 4; t += 256) {
      int r = t >> 5;
      int cc = (t & 31) << 2;
      *(float4*)&Bs[r][cc] = *(const float4*)(B + (size_t)(k0 + r) * Nc + block_col + cc);
    }
    __syncthreads();
    #pragma unroll
    for (int k = 0; k < BK; ++k) {
      float a[8], b[8];
      *(float4*)&a[0] = *(const float4*)&As[k][tr];
      *(float4*)&a[4] = *(const float4*)&As[k][tr + 4];
      *(float4*)&b[0] = *(const float4*)&Bs[k][tc];
      *(float4*)&b[4] = *(const float4*)&Bs[k][tc + 4];
      #pragma unroll
      for (int i = 0; i < 8; ++i)
        #pragma unroll
        for (int j = 0; j < 8; ++j)
          acc[i][j] = fmaf(a[i], b[j], acc[i][j]);
    }
    __syncthreads();
  }
  int col0 = block_col + tc;                 // multiple of 8
  size_t base = ((size_t)(col0 >> 4) * M) * 16 + (col0 & 15);
  for (int i = 0; i < 8; ++i) {
    int gr = block_row + tr + i;
    if (gr >= M) break;
    float s = dis[gr];
    float4 v0 = {acc[i][0] * s, acc[i][1] * s, acc[i][2] * s, acc[i][3] * s};
    float4 v1 = {acc[i][4] * s, acc[i][5] * s, acc[i][6] * s, acc[i][7] * s};
    float* cp = C + base + (size_t)gr * 16;
    *(float4*)cp = v0;
    *(float4*)(cp + 4) = v1;
  }
}

// ---------------- XCD-pinned sliced aggregation ----------------
// hs : [NSLICE][N][16] slice-major (already scaled by dis[src]).
// Blocks round-robin to XCDs (blockIdx&7); XCD x processes slices {x, x+8,...}
// sequentially, so each XCD's 4MiB L2 holds exactly its own 3.2MB slice.
// Persistent grid (all blocks resident). Wave = 8 nodes; per node 8 lanes =
// 2 edge-parallel x 4 float4-chunks; batch-4 gathers; one shfl_xor(4) round.
template <int FCH, bool OUTSLICE>
__global__ __launch_bounds__(256) void k_agg_xcd(const float* __restrict__ hs,
                                                 const int* __restrict__ rowptr,
                                                 const int* __restrict__ csr,
                                                 const float* __restrict__ dis,
                                                 const float* __restrict__ bias,
                                                 float* __restrict__ out,
                                                 int N, int do_relu) {
  const int NSLICE = FCH / 16;
  int bid = blockIdx.x;
  int xcd = bid & 7;
  int wid = threadIdx.x >> 6;
  int lane = threadIdx.x & 63;
  int sub = lane >> 3;          // node within chunk (0..7)
  int epar = (lane >> 2) & 1;   // edge-parallel 0/1
  int c2 = lane & 3;            // float4 chunk of 16-ch row
  int wix = ((bid >> 3) << 2) + wid;           // wave index within XCD
  int wpx = ((int)(gridDim.x >> 3)) << 2;      // waves per XCD
  int nchunk = (N + 7) >> 3;

  for (int ph = 0; ph < NSLICE / 8; ++ph) {
    int s = xcd + (ph << 3);
    const float* in = hs + (size_t)s * N * 16;
    for (int ch = wix; ch < nchunk; ch += wpx) {
      int node = (ch << 3) + sub;
      bool valid = node < N;
      int b0 = 0, e0 = 0;
      if (valid) { b0 = rowptr[node]; e0 = rowptr[node + 1]; }
      float4 acc = {0.f, 0.f, 0.f, 0.f};
      int j = b0 + epar;
      for (; j + 6 < e0; j += 8) {
        int i0 = csr[j];     int i1 = csr[j + 2];
        int i2 = csr[j + 4]; int i3 = csr[j + 6];
        float4 v0 = *(const float4*)(in + ((size_t)i0 << 4) + (c2 << 2));
        float4 v1 = *(const float4*)(in + ((size_t)i1 << 4) + (c2 << 2));
        float4 v2 = *(const float4*)(in + ((size_t)i2 << 4) + (c2 << 2));
        float4 v3 = *(const float4*)(in + ((size_t)i3 << 4) + (c2 << 2));
        acc.x += (v0.x + v1.x) + (v2.x + v3.x);
        acc.y += (v0.y + v1.y) + (v2.y + v3.y);
        acc.z += (v0.z + v1.z) + (v2.z + v3.z);
        acc.w += (v0.w + v1.w) + (v2.w + v3.w);
      }
      for (; j < e0; j += 2) {
        int idx = csr[j];
        float4 v = *(const float4*)(in + ((size_t)idx << 4) + (c2 << 2));
        acc.x += v.x; acc.y += v.y; acc.z += v.z; acc.w += v.w;
      }
      acc.x += __shfl_xor(acc.x, 4);
      acc.y += __shfl_xor(acc.y, 4);
      acc.z += __shfl_xor(acc.z, 4);
      acc.w += __shfl_xor(acc.w, 4);
      if (valid && epar == 0) {
        float4 self = *(const float4*)(in + ((size_t)node << 4) + (c2 << 2));
        float dn = dis[node];
        int col = (s << 4) + (c2 << 2);
        float4 bv = *(const float4*)(bias + col);
        float4 r;
        r.x = (acc.x + self.x) * dn + bv.x;
        r.y = (acc.y + self.y) * dn + bv.y;
        r.z = (acc.z + self.z) * dn + bv.z;
        r.w = (acc.w + self.w) * dn + bv.w;
        if (do_relu) {
          r.x = fmaxf(r.x, 0.f); r.y = fmaxf(r.y, 0.f);
          r.z = fmaxf(r.z, 0.f); r.w = fmaxf(r.w, 0.f);
        }
        if (OUTSLICE)
          *(float4*)(out + (size_t)s * N * 16 + ((size_t)node << 4) + (c2 << 2)) = r;
        else
          *(float4*)(out + (size_t)node * FCH + col) = r;
      }
    }
  }
}

// ---------------- XCD-pinned decode: per-slice partial dots, no atomics ----------------
// z : [8][N][16] slice-major. XCD x handles slice x for ALL edges; partial
// dot written to partial[x*E + e]; reduce kernel sums the 8 partials.
__global__ __launch_bounds__(256) void k_decode_xcd(const float* __restrict__ z,
                                                    const int* __restrict__ src,
                                                    const int* __restrict__ dst,
                                                    float* __restrict__ partial,
                                                    int E, int N) {
  int bid = blockIdx.x;
  int xcd = bid & 7;
  int tix = ((bid >> 3) << 8) + threadIdx.x;      // thread index within XCD
  int tpx = ((int)(gridDim.x >> 3)) << 8;         // threads per XCD
  const float* zc = z + (size_t)xcd * N * 16;
  float* pp = partial + (size_t)xcd * E;
  for (int e = tix; e < E; e += tpx) {
    int a = src[e], b = dst[e];
    const float4* pa = (const float4*)(zc + ((size_t)a << 4));
    const float4* pb = (const float4*)(zc + ((size_t)b << 4));
    float4 a0 = pa[0], a1 = pa[1], a2 = pa[2], a3 = pa[3];
    float4 b0 = pb[0], b1 = pb[1], b2 = pb[2], b3 = pb[3];
    float p = a0.x * b0.x + a0.y * b0.y + a0.z * b0.z + a0.w * b0.w;
    p += a1.x * b1.x + a1.y * b1.y + a1.z * b1.z + a1.w * b1.w;
    p += a2.x * b2.x + a2.y * b2.y + a2.z * b2.z + a2.w * b2.w;
    p += a3.x * b3.x + a3.y * b3.y + a3.z * b3.z + a3.w * b3.w;
    pp[e] = p;
  }
}

__global__ void k_dreduce(const float* __restrict__ partial, float* __restrict__ out, int E) {
  int e = blockIdx.x * 256 + threadIdx.x;
  if (e >= E) return;
  float s = 0.f;
  #pragma unroll
  for (int k = 0; k < 8; ++k) s += partial[(size_t)k * E + e];
  out[e] = s;
}

extern "C" void kernel_launch(void* const* d_in, const int* in_sizes, int n_in,
                              void* d_out, int out_size, void* d_ws, size_t ws_size,
                              hipStream_t stream) {
  const float* x  = (const float*)d_in[0];
  const int* eidx = (const int*)d_in[1];
  const float* W1 = (const float*)d_in[2];
  const float* b1 = (const float*)d_in[3];
  const float* W2 = (const float*)d_in[4];
  const float* b2 = (const float*)d_in[5];
  float* out = (float*)d_out;

  const int IN_CH = 256, HID = 256, OUT_CH = 128;
  const int N = in_sizes[0] / IN_CH;
  const int E = in_sizes[1] / 2;
  const int* esrc = eidx;
  const int* edst = eidx + E;

  char* p = (char*)d_ws;
  auto alloc = [&](size_t bytes) -> char* { char* r = p; p += WS_ALIGN(bytes); return r; };
  int*   deg    = (int*)  alloc(sizeof(int) * N);
  float* dis    = (float*)alloc(sizeof(float) * N);
  int*   rowptr = (int*)  alloc(sizeof(int) * (N + 1));
  int*   cursor = (int*)  alloc(sizeof(int) * N);
  int*   csr    = (int*)  alloc(sizeof(int) * (size_t)E);
  float* bufA   = (float*)alloc(sizeof(float) * (size_t)N * HID);  // h1s / h2s; reused as decode partials
  float* bufB   = (float*)alloc(sizeof(float) * (size_t)N * HID);  // z1 (row-major) / z2 (slice-major)

  const int T = 256;
  hipLaunchKernelGGL(k_init_deg, dim3((N + T - 1) / T), dim3(T), 0, stream, deg, N);
  hipLaunchKernelGGL(k_count, dim3((E + T - 1) / T), dim3(T), 0, stream, edst, E, deg);
  hipLaunchKernelGGL(k_dis, dim3((N + T - 1) / T), dim3(T), 0, stream, deg, dis, N);
  hipLaunchKernelGGL(k_scan, dim3(1), dim3(1024), 0, stream, deg, rowptr, cursor, N, E);
  hipLaunchKernelGGL(k_fill, dim3((E + T - 1) / T), dim3(T), 0, stream, esrc, edst, E, cursor, csr);

  const int PG = 1024;  // persistent grid: 4 blocks/CU, all resident, 128 blocks/XCD

  // conv1: h1s = (x @ W1)*dis[row] slice-major; z1 = relu(...) row-major
  dim3 g1((N + BM - 1) / BM, HID / BN);
  hipLaunchKernelGGL(k_gemm_scale_sm, g1, dim3(256), 0, stream, x, W1, dis, bufA, N, HID, IN_CH);
  hipLaunchKernelGGL((k_agg_xcd<256, false>), dim3(PG), dim3(256), 0, stream,
                     bufA, rowptr, csr, dis, b1, bufB, N, 1);

  // conv2: h2s = (z1 @ W2)*dis[row] slice-major; z2 slice-major
  dim3 g2((N + BM - 1) / BM, OUT_CH / BN);
  hipLaunchKernelGGL(k_gemm_scale_sm, g2, dim3(256), 0, stream, bufB, W2, dis, bufA, N, OUT_CH, HID);
  hipLaunchKernelGGL((k_agg_xcd<128, true>), dim3(PG), dim3(256), 0, stream,
                     bufA, rowptr, csr, dis, b2, bufB, N, 0);

  // decode: per-XCD slice partial dots into bufA (h2s dead), then reduce
  hipLaunchKernelGGL(k_decode_xcd, dim3(PG), dim3(256), 0, stream,
                     bufB, esrc, edst, bufA, E, N);
  hipLaunchKernelGGL(k_dreduce, dim3((E + 255) / 256), dim3(256), 0, stream,
                     bufA, out, E);
}

// Round 8
// 824.908 us; speedup vs baseline: 1.6901x; 1.0824x over previous
//
#include <hip/hip_runtime.h>

#define WS_ALIGN(x) (((x) + 255) & ~(size_t)255)

// ---------------- degree / norm ----------------
__global__ void k_init_deg(int* deg, int N) {
  int i = blockIdx.x * blockDim.x + threadIdx.x;
  if (i < N) deg[i] = 1;  // self-loop
}

__global__ void k_count(const int* __restrict__ dst, int E, int* __restrict__ deg) {
  int e = blockIdx.x * blockDim.x + threadIdx.x;
  if (e < E) atomicAdd(&deg[dst[e]], 1);
}

__global__ void k_dis(const int* __restrict__ deg, float* __restrict__ dis, int N) {
  int i = blockIdx.x * blockDim.x + threadIdx.x;
  if (i < N) dis[i] = rsqrtf((float)deg[i]);
}

// ---------------- CSR build ----------------
__global__ __launch_bounds__(1024) void k_scan(const int* __restrict__ deg,
                                               int* __restrict__ rowptr,
                                               int* __restrict__ cursor,
                                               int N, int Etot) {
  __shared__ int wsum[16];
  __shared__ int s_carry;
  int tid = threadIdx.x, lane = tid & 63, w = tid >> 6;
  if (tid == 0) { s_carry = 0; rowptr[N] = Etot; }
  __syncthreads();
  for (int base = 0; base < N; base += 4096) {
    int i0 = base + tid * 4;
    int v[4];
    #pragma unroll
    for (int u = 0; u < 4; ++u) {
      int i = i0 + u;
      v[u] = (i < N) ? (deg[i] - 1) : 0;
    }
    int tsum = v[0] + v[1] + v[2] + v[3];
    int sc = tsum;
    #pragma unroll
    for (int off = 1; off < 64; off <<= 1) {
      int t = __shfl_up(sc, off);
      if (lane >= off) sc += t;
    }
    if (lane == 63) wsum[w] = sc;
    __syncthreads();
    if (w == 0 && lane < 16) {
      int xx = wsum[lane];
      #pragma unroll
      for (int off = 1; off < 16; off <<= 1) {
        int t = __shfl_up(xx, off);
        if (lane >= off) xx += t;
      }
      wsum[lane] = xx;
    }
    __syncthreads();
    int woff = (w == 0) ? 0 : wsum[w - 1];
    int excl = s_carry + woff + (sc - tsum);
    #pragma unroll
    for (int u = 0; u < 4; ++u) {
      int i = i0 + u;
      if (i < N) { rowptr[i] = excl; cursor[i] = excl; }
      excl += v[u];
    }
    __syncthreads();
    if (tid == 0) s_carry += wsum[15];
    __syncthreads();
  }
}

__global__ void k_fill(const int* __restrict__ src, const int* __restrict__ dst, int E,
                       int* __restrict__ cursor, int* __restrict__ csr_src) {
  int e = blockIdx.x * blockDim.x + threadIdx.x;
  if (e < E) {
    int d = dst[e];
    int pos = atomicAdd(&cursor[d], 1);
    csr_src[pos] = src[e];
  }
}

// ---------------- GEMM: writes C in SLICE-MAJOR: C[(col/16)*M + row][col%16] ----------------
// C[m][n] = (sum_k A[m][k]*B[k][n]) * dis[m]
#define BM 128
#define BN 128
#define BK 16
__global__ __launch_bounds__(256) void k_gemm_scale_sm(const float* __restrict__ A,
                                                       const float* __restrict__ B,
                                                       const float* __restrict__ dis,
                                                       float* __restrict__ C,
                                                       int M, int Nc, int K) {
  __shared__ float As[BK][BM];
  __shared__ float Bs[BK][BN];
  int tid = threadIdx.x;
  int block_row = blockIdx.x * BM;
  int block_col = blockIdx.y * BN;
  int tr = (tid >> 4) << 3;
  int tc = (tid & 15) << 3;
  float acc[8][8] = {};
  for (int k0 = 0; k0 < K; k0 += BK) {
    for (int t = tid; t < BM * BK / 4; t += 256) {
      int r = t >> 2;
      int cc = (t & 3) << 2;
      int gr = block_row + r;
      float4 v = {0.f, 0.f, 0.f, 0.f};
      if (gr < M) v = *(const float4*)(A + (size_t)gr * K + k0 + cc);
      As[cc + 0][r] = v.x; As[cc + 1][r] = v.y; As[cc + 2][r] = v.z; As[cc + 3][r] = v.w;
    }
    for (int t = tid; t < BK * BN / 4; t += 256) {
      int r = t >> 5;
      int cc = (t & 31) << 2;
      *(float4*)&Bs[r][cc] = *(const float4*)(B + (size_t)(k0 + r) * Nc + block_col + cc);
    }
    __syncthreads();
    #pragma unroll
    for (int k = 0; k < BK; ++k) {
      float a[8], b[8];
      *(float4*)&a[0] = *(const float4*)&As[k][tr];
      *(float4*)&a[4] = *(const float4*)&As[k][tr + 4];
      *(float4*)&b[0] = *(const float4*)&Bs[k][tc];
      *(float4*)&b[4] = *(const float4*)&Bs[k][tc + 4];
      #pragma unroll
      for (int i = 0; i < 8; ++i)
        #pragma unroll
        for (int j = 0; j < 8; ++j)
          acc[i][j] = fmaf(a[i], b[j], acc[i][j]);
    }
    __syncthreads();
  }
  int col0 = block_col + tc;                 // multiple of 8
  size_t base = ((size_t)(col0 >> 4) * M) * 16 + (col0 & 15);
  for (int i = 0; i < 8; ++i) {
    int gr = block_row + tr + i;
    if (gr >= M) break;
    float s = dis[gr];
    float4 v0 = {acc[i][0] * s, acc[i][1] * s, acc[i][2] * s, acc[i][3] * s};
    float4 v1 = {acc[i][4] * s, acc[i][5] * s, acc[i][6] * s, acc[i][7] * s};
    float* cp = C + base + (size_t)gr * 16;
    *(float4*)cp = v0;
    *(float4*)(cp + 4) = v1;
  }
}

// ---------------- XCD-pinned sliced aggregation ----------------
// hs : [NSLICE][N][16] slice-major (already scaled by dis[src]).
// Blocks round-robin to XCDs (blockIdx&7); XCD x processes slices {x, x+8,...}
// sequentially, so each XCD's 4MiB L2 holds exactly its own 3.2MB slice.
// Persistent grid. Wave = 8 nodes; per node 8 lanes = 2 edge-parallel x
// 4 float4-chunks (4 lanes share each gathered 64B row -> coalesced).
template <int FCH, bool OUTSLICE>
__global__ __launch_bounds__(256) void k_agg_xcd(const float* __restrict__ hs,
                                                 const int* __restrict__ rowptr,
                                                 const int* __restrict__ csr,
                                                 const float* __restrict__ dis,
                                                 const float* __restrict__ bias,
                                                 float* __restrict__ out,
                                                 int N, int do_relu) {
  const int NSLICE = FCH / 16;
  int bid = blockIdx.x;
  int xcd = bid & 7;
  int wid = threadIdx.x >> 6;
  int lane = threadIdx.x & 63;
  int sub = lane >> 3;          // node within chunk (0..7)
  int epar = (lane >> 2) & 1;   // edge-parallel 0/1
  int c2 = lane & 3;            // float4 chunk of 16-ch row
  int wix = ((bid >> 3) << 2) + wid;           // wave index within XCD
  int wpx = ((int)(gridDim.x >> 3)) << 2;      // waves per XCD
  int nchunk = (N + 7) >> 3;

  for (int ph = 0; ph < NSLICE / 8; ++ph) {
    int s = xcd + (ph << 3);
    const float* in = hs + (size_t)s * N * 16;
    for (int ch = wix; ch < nchunk; ch += wpx) {
      int node = (ch << 3) + sub;
      bool valid = node < N;
      int b0 = 0, e0 = 0;
      if (valid) { b0 = rowptr[node]; e0 = rowptr[node + 1]; }
      float4 acc = {0.f, 0.f, 0.f, 0.f};
      int j = b0 + epar;
      for (; j + 6 < e0; j += 8) {
        int i0 = csr[j];     int i1 = csr[j + 2];
        int i2 = csr[j + 4]; int i3 = csr[j + 6];
        float4 v0 = *(const float4*)(in + ((size_t)i0 << 4) + (c2 << 2));
        float4 v1 = *(const float4*)(in + ((size_t)i1 << 4) + (c2 << 2));
        float4 v2 = *(const float4*)(in + ((size_t)i2 << 4) + (c2 << 2));
        float4 v3 = *(const float4*)(in + ((size_t)i3 << 4) + (c2 << 2));
        acc.x += (v0.x + v1.x) + (v2.x + v3.x);
        acc.y += (v0.y + v1.y) + (v2.y + v3.y);
        acc.z += (v0.z + v1.z) + (v2.z + v3.z);
        acc.w += (v0.w + v1.w) + (v2.w + v3.w);
      }
      for (; j < e0; j += 2) {
        int idx = csr[j];
        float4 v = *(const float4*)(in + ((size_t)idx << 4) + (c2 << 2));
        acc.x += v.x; acc.y += v.y; acc.z += v.z; acc.w += v.w;
      }
      acc.x += __shfl_xor(acc.x, 4);
      acc.y += __shfl_xor(acc.y, 4);
      acc.z += __shfl_xor(acc.z, 4);
      acc.w += __shfl_xor(acc.w, 4);
      if (valid && epar == 0) {
        float4 self = *(const float4*)(in + ((size_t)node << 4) + (c2 << 2));
        float dn = dis[node];
        int col = (s << 4) + (c2 << 2);
        float4 bv = *(const float4*)(bias + col);
        float4 r;
        r.x = (acc.x + self.x) * dn + bv.x;
        r.y = (acc.y + self.y) * dn + bv.y;
        r.z = (acc.z + self.z) * dn + bv.z;
        r.w = (acc.w + self.w) * dn + bv.w;
        if (do_relu) {
          r.x = fmaxf(r.x, 0.f); r.y = fmaxf(r.y, 0.f);
          r.z = fmaxf(r.z, 0.f); r.w = fmaxf(r.w, 0.f);
        }
        if (OUTSLICE)
          *(float4*)(out + (size_t)s * N * 16 + ((size_t)node << 4) + (c2 << 2)) = r;
        else
          *(float4*)(out + (size_t)node * FCH + col) = r;
      }
    }
  }
}

// ---------------- XCD-pinned decode, coalesced 4-lane rows ----------------
// z : [8][N][16] slice-major. XCD x handles slice x for ALL edges.
// sub=lane>>2 owns an edge; c2=lane&3 owns a float4 of each 64B row
// (4 lanes share a cache line -> 2 transactions/edge instead of 8).
// 32 edges per wave-iteration (x2 unroll) for MLP. Partial dots to
// partial[x*E+e]; k_dreduce sums the 8 slices.
__global__ __launch_bounds__(256) void k_decode_xcd4(const float* __restrict__ z,
                                                     const int* __restrict__ src,
                                                     const int* __restrict__ dst,
                                                     float* __restrict__ partial,
                                                     int E, int N) {
  int bid = blockIdx.x;
  int xcd = bid & 7;
  int wid = threadIdx.x >> 6;
  int lane = threadIdx.x & 63;
  int c2 = lane & 3;
  int sub = lane >> 2;                          // 0..15
  int wix = ((bid >> 3) << 2) + wid;            // wave index within XCD
  int wpx = ((int)(gridDim.x >> 3)) << 2;       // waves per XCD
  const float* zc = z + (size_t)xcd * N * 16;
  float* pp = partial + (size_t)xcd * E;

  for (int e0 = wix * 32; e0 < E; e0 += wpx * 32) {
    int eA = e0 + sub;
    int eB = e0 + 16 + sub;
    bool vA = eA < E, vB = eB < E;
    int aA = 0, dA = 0, aB = 0, dB = 0;
    if (vA) { aA = src[eA]; dA = dst[eA]; }
    if (vB) { aB = src[eB]; dB = dst[eB]; }
    float pA = 0.f, pB = 0.f;
    if (vA) {
      float4 za = *(const float4*)(zc + ((size_t)aA << 4) + (c2 << 2));
      float4 zb = *(const float4*)(zc + ((size_t)dA << 4) + (c2 << 2));
      pA = za.x * zb.x + za.y * zb.y + za.z * zb.z + za.w * zb.w;
    }
    if (vB) {
      float4 za = *(const float4*)(zc + ((size_t)aB << 4) + (c2 << 2));
      float4 zb = *(const float4*)(zc + ((size_t)dB << 4) + (c2 << 2));
      pB = za.x * zb.x + za.y * zb.y + za.z * zb.z + za.w * zb.w;
    }
    pA += __shfl_xor(pA, 1);
    pA += __shfl_xor(pA, 2);
    pB += __shfl_xor(pB, 1);
    pB += __shfl_xor(pB, 2);
    if (c2 == 0) {
      if (vA) pp[eA] = pA;
      if (vB) pp[eB] = pB;
    }
  }
}

__global__ void k_dreduce(const float* __restrict__ partial, float* __restrict__ out, int E) {
  int e = blockIdx.x * 256 + threadIdx.x;
  if (e >= E) return;
  float s = 0.f;
  #pragma unroll
  for (int k = 0; k < 8; ++k) s += partial[(size_t)k * E + e];
  out[e] = s;
}

extern "C" void kernel_launch(void* const* d_in, const int* in_sizes, int n_in,
                              void* d_out, int out_size, void* d_ws, size_t ws_size,
                              hipStream_t stream) {
  const float* x  = (const float*)d_in[0];
  const int* eidx = (const int*)d_in[1];
  const float* W1 = (const float*)d_in[2];
  const float* b1 = (const float*)d_in[3];
  const float* W2 = (const float*)d_in[4];
  const float* b2 = (const float*)d_in[5];
  float* out = (float*)d_out;

  const int IN_CH = 256, HID = 256, OUT_CH = 128;
  const int N = in_sizes[0] / IN_CH;
  const int E = in_sizes[1] / 2;
  const int* esrc = eidx;
  const int* edst = eidx + E;

  char* p = (char*)d_ws;
  auto alloc = [&](size_t bytes) -> char* { char* r = p; p += WS_ALIGN(bytes); return r; };
  int*   deg    = (int*)  alloc(sizeof(int) * N);
  float* dis    = (float*)alloc(sizeof(float) * N);
  int*   rowptr = (int*)  alloc(sizeof(int) * (N + 1));
  int*   cursor = (int*)  alloc(sizeof(int) * N);
  int*   csr    = (int*)  alloc(sizeof(int) * (size_t)E);
  float* bufA   = (float*)alloc(sizeof(float) * (size_t)N * HID);  // h1s / h2s; reused as decode partials
  float* bufB   = (float*)alloc(sizeof(float) * (size_t)N * HID);  // z1 (row-major) / z2 (slice-major)

  const int T = 256;
  hipLaunchKernelGGL(k_init_deg, dim3((N + T - 1) / T), dim3(T), 0, stream, deg, N);
  hipLaunchKernelGGL(k_count, dim3((E + T - 1) / T), dim3(T), 0, stream, edst, E, deg);
  hipLaunchKernelGGL(k_dis, dim3((N + T - 1) / T), dim3(T), 0, stream, deg, dis, N);
  hipLaunchKernelGGL(k_scan, dim3(1), dim3(1024), 0, stream, deg, rowptr, cursor, N, E);
  hipLaunchKernelGGL(k_fill, dim3((E + T - 1) / T), dim3(T), 0, stream, esrc, edst, E, cursor, csr);

  const int PG = 2048;  // persistent grid: 8 blocks/CU (32 waves/CU), 256/XCD

  // conv1: h1s = (x @ W1)*dis[row] slice-major; z1 = relu(...) row-major
  dim3 g1((N + BM - 1) / BM, HID / BN);
  hipLaunchKernelGGL(k_gemm_scale_sm, g1, dim3(256), 0, stream, x, W1, dis, bufA, N, HID, IN_CH);
  hipLaunchKernelGGL((k_agg_xcd<256, false>), dim3(PG), dim3(256), 0, stream,
                     bufA, rowptr, csr, dis, b1, bufB, N, 1);

  // conv2: h2s = (z1 @ W2)*dis[row] slice-major; z2 slice-major
  dim3 g2((N + BM - 1) / BM, OUT_CH / BN);
  hipLaunchKernelGGL(k_gemm_scale_sm, g2, dim3(256), 0, stream, bufB, W2, dis, bufA, N, OUT_CH, HID);
  hipLaunchKernelGGL((k_agg_xcd<128, true>), dim3(PG), dim3(256), 0, stream,
                     bufA, rowptr, csr, dis, b2, bufB, N, 0);

  // decode: per-XCD slice partial dots into bufA (h2s dead), then reduce
  hipLaunchKernelGGL(k_decode_xcd4, dim3(PG), dim3(256), 0, stream,
                     bufB, esrc, edst, bufA, E, N);
  hipLaunchKernelGGL(k_dreduce, dim3((E + 255) / 256), dim3(256), 0, stream,
                     bufA, out, E);
}